// Round 4
// baseline (63.658 us; speedup 1.0000x reference)
//
#include <hip/hip_runtime.h>
#include <math.h>

#define RED_BLOCKS 1024
#define BLK 256
#define HDIM 64

typedef int   v4i __attribute__((ext_vector_type(4)));
typedef float v4f __attribute__((ext_vector_type(4)));

// ---------------- Stage 1: per-block partial sum / sumsq (f64, deterministic) ----------------
__global__ void __launch_bounds__(BLK) k_reduce_partial(const float* __restrict__ hu, int n,
                                                        double* __restrict__ part) {
  __shared__ double ls[BLK];
  __shared__ double lq[BLK];
  const v4f* hu4 = (const v4f*)hu;
  const int n4 = n >> 2;
  double s = 0.0, q = 0.0;
  for (int i = blockIdx.x * BLK + threadIdx.x; i < n4; i += RED_BLOCKS * BLK) {
    v4f v = hu4[i];
    double a = (double)v.x, b = (double)v.y, c = (double)v.z, d = (double)v.w;
    s += a + b + c + d;
    q += a * a + b * b + c * c + d * d;
  }
  // tail (n not multiple of 4): block 0 / thread 0, fixed order -> deterministic
  if (blockIdx.x == 0 && threadIdx.x == 0) {
    for (int i = n4 << 2; i < n; ++i) {
      double v = (double)hu[i];
      s += v;
      q += v * v;
    }
  }
  ls[threadIdx.x] = s;
  lq[threadIdx.x] = q;
  __syncthreads();
  for (int off = BLK / 2; off > 0; off >>= 1) {
    if (threadIdx.x < off) {
      ls[threadIdx.x] += ls[threadIdx.x + off];
      lq[threadIdx.x] += lq[threadIdx.x + off];
    }
    __syncthreads();
  }
  if (threadIdx.x == 0) {
    part[blockIdx.x] = ls[0];
    part[RED_BLOCKS + blockIdx.x] = lq[0];
  }
}

// ---------------- Stage 2: final reduce -> mu, 1/(std+eps) ----------------
__global__ void __launch_bounds__(BLK) k_reduce_final(const double* __restrict__ part, int n,
                                                      float* __restrict__ stats) {
  __shared__ double ls[BLK];
  __shared__ double lq[BLK];
  double s = 0.0, q = 0.0;
  for (int i = threadIdx.x; i < RED_BLOCKS; i += BLK) {
    s += part[i];
    q += part[RED_BLOCKS + i];
  }
  ls[threadIdx.x] = s;
  lq[threadIdx.x] = q;
  __syncthreads();
  for (int off = BLK / 2; off > 0; off >>= 1) {
    if (threadIdx.x < off) {
      ls[threadIdx.x] += ls[threadIdx.x + off];
      lq[threadIdx.x] += lq[threadIdx.x + off];
    }
    __syncthreads();
  }
  if (threadIdx.x == 0) {
    double sum = ls[0], sumsq = lq[0];
    double mu = sum / (double)n;
    double var = (sumsq - sum * sum / (double)n) / (double)(n - 1);
    if (var < 0.0) var = 0.0;
    double sigma = sqrt(var) + 1e-8;  // torch-style unbiased std + EPS
    stats[0] = (float)mu;
    stats[1] = (float)(1.0 / sigma);
  }
}

// ---------------- Stage 3: per-node s_nei / s_self (vectorized weight loop) ----------------
__global__ void __launch_bounds__(BLK) k_layer1(
    const float* __restrict__ hu,
    const int* __restrict__ nbr,
    const float* __restrict__ Wn1,
    const float* __restrict__ Ws1,
    const float* __restrict__ B1,
    const float* __restrict__ Wn2,
    const float* __restrict__ Ws2,
    const float* __restrict__ stats,
    float* __restrict__ snei,
    float* __restrict__ sself,
    int n) {
  __shared__ v4f wn1v[HDIM / 4], ws1v[HDIM / 4], bb1v[HDIM / 4], wn2v[HDIM / 4], ws2v[HDIM / 4];
  int t = threadIdx.x;
  if (t < HDIM) {
    ((float*)wn1v)[t] = Wn1[t];
    ((float*)ws1v)[t] = Ws1[t];
    ((float*)bb1v)[t] = B1[t];
    ((float*)wn2v)[t] = Wn2[t];
    ((float*)ws2v)[t] = Ws2[t];
  }
  __syncthreads();
  int u = blockIdx.x * BLK + threadIdx.x;
  if (u >= n) return;
  const float mu = stats[0];
  const float inv = stats[1];
  v4i nb = __builtin_nontemporal_load((const v4i*)nbr + u);  // streamed once; keep hu in L2
  float hsum = hu[nb.x] + hu[nb.y] + hu[nb.z] + hu[nb.w];
  float a = (hsum - 4.0f * mu) * inv;
  float c = (hu[u] - mu) * inv;
  v4f av = {a, a, a, a};
  v4f cv = {c, c, c, c};
  v4f z = {0.0f, 0.0f, 0.0f, 0.0f};
  v4f sn4 = z, ss4 = z;
#pragma unroll
  for (int j = 0; j < HDIM / 4; ++j) {
    v4f tt = av * wn1v[j] + cv * ws1v[j] + bb1v[j];  // packed fma
    v4f r = __builtin_elementwise_max(tt, z);
    sn4 += r * wn2v[j];
    ss4 += r * ws2v[j];
  }
  float sn = (sn4.x + sn4.y) + (sn4.z + sn4.w);
  float ss = (ss4.x + ss4.y) + (ss4.z + ss4.w);
  // write-once streams: bypass L2 so hu stays resident during this kernel
  __builtin_nontemporal_store(sn, snei + u);
  __builtin_nontemporal_store(ss, sself + u);
}

// ---------------- Stage 4: gather s_nei + tanh ----------------
__global__ void __launch_bounds__(BLK) k_layer2(
    const int* __restrict__ nbr,
    const float* __restrict__ snei,
    const float* __restrict__ sself,
    const float* __restrict__ B2,
    float* __restrict__ out,
    int n) {
  int u = blockIdx.x * BLK + threadIdx.x;
  if (u >= n) return;
  v4i nb = __builtin_nontemporal_load((const v4i*)nbr + u);  // keep snei in L2 instead
  float s = snei[nb.x] + snei[nb.y] + snei[nb.z] + snei[nb.w];
  float ss = __builtin_nontemporal_load(sself + u);
  float d = B2[0] + s + ss;
  __builtin_nontemporal_store(0.3f * tanhf(d), out + u);
}

extern "C" void kernel_launch(void* const* d_in, const int* in_sizes, int n_in,
                              void* d_out, int out_size, void* d_ws, size_t ws_size,
                              hipStream_t stream) {
  const float* hu  = (const float*)d_in[0];
  const int*   nbr = (const int*)d_in[1];
  // d_in[2] = neighbor_offsets: fixed-degree-4 CSR (arange*4), not needed.
  const float* Wn1 = (const float*)d_in[3];
  const float* Ws1 = (const float*)d_in[4];
  const float* B1  = (const float*)d_in[5];
  const float* Wn2 = (const float*)d_in[6];
  const float* Ws2 = (const float*)d_in[7];
  const float* B2  = (const float*)d_in[8];
  float* out = (float*)d_out;
  const int n = in_sizes[0];

  char* ws = (char*)d_ws;
  double* part = (double*)ws;                        // 2*RED_BLOCKS*8 = 16 KiB
  float* stats = (float*)(ws + 2 * RED_BLOCKS * 8);  // 8 B
  float* snei  = (float*)(ws + 32768);               // n*4 B
  float* sself = snei + n;                           // n*4 B

  k_reduce_partial<<<RED_BLOCKS, BLK, 0, stream>>>(hu, n, part);
  k_reduce_final<<<1, BLK, 0, stream>>>(part, n, stats);

  int blocks = (n + BLK - 1) / BLK;
  k_layer1<<<blocks, BLK, 0, stream>>>(hu, nbr, Wn1, Ws1, B1, Wn2, Ws2, stats,
                                       snei, sself, n);
  k_layer2<<<blocks, BLK, 0, stream>>>(nbr, snei, sself, B2, out, n);
}